// Round 5
// baseline (116.223 us; speedup 1.0000x reference)
//
#include <hip/hip_runtime.h>
#include <hip/hip_fp16.h>

// N=1536 T=20 H=64 E=16 M=128
// pre1[i,j] = Q[j] - P[i]  (Q,P: N x 128 fp16 in d_ws; W2T: 64x128 fp16 in d_ws)
// out[i]    = max_j relu( relu(Q[j]-P[i]) @ W2 + b2 )
//
// R5: JSPLIT 4->6 (3072 blocks = 12/CU; 3 waves/SIMD if regs <= 170),
// zero-C MFMA peel (no per-tile acc zero-init), 2x-unrolled q double-buffer
// (no qc<-qn copies, no bottom-of-loop vmcnt(0) serialization), b2+relu
// deferred out of the tile loop (max_j relu(acc+b2) = relu(max_j acc + b2)),
// W2^T staged as fp16 by precompute (bfrag = 16 vector loads, was 128 scalar).

#define NN 1536
#define HH 64
#define EE 16
#define MM 128
#define TT 20
#define NI 3
#define JSPLIT 6
#define NIGRP (NN / NI)      // 512 i-groups
#define NTILE (96 / JSPLIT)  // 16 j-tiles of 16 per wave (even, for 2x unroll)

typedef _Float16 half8 __attribute__((ext_vector_type(8)));
typedef float f32x4 __attribute__((ext_vector_type(4)));

// grid NN, block 128. Computes Q,P,W2T (fp16) and zero-inits out (poisoned 0xAA).
__global__ __launch_bounds__(128) void precompute_kernel(
    const float* __restrict__ hidden, const float* __restrict__ gt,
    const float* __restrict__ We, const float* __restrict__ be,
    const float* __restrict__ W1, const float* __restrict__ b1,
    const float* __restrict__ W2,
    _Float16* __restrict__ Q, _Float16* __restrict__ P,
    _Float16* __restrict__ W2T, float* __restrict__ out)
{
  const int j = blockIdx.x;
  const int m = threadIdx.x;
  const float* hrow = hidden + j * HH;
  float a = 0.f;
  #pragma unroll 8
  for (int h = 0; h < HH; ++h) a = fmaf(hrow[h], W1[h * MM + m], a);
  float ve0 = 0.f, ve1 = 0.f, cm = b1[m];
  #pragma unroll
  for (int e = 0; e < EE; ++e) {
    float w1e = W1[(HH + e) * MM + m];
    ve0 = fmaf(We[e], w1e, ve0);       // We[0][e]
    ve1 = fmaf(We[EE + e], w1e, ve1);  // We[1][e]
    cm  = fmaf(be[e], w1e, cm);
  }
  const float e0 = gt[j * (2 * TT) + 2 * (TT - 1)];
  const float e1 = gt[j * (2 * TT) + 2 * (TT - 1) + 1];
  const float p = fmaf(e0, ve0, e1 * ve1);
  P[j * MM + m] = (_Float16)p;
  Q[j * MM + m] = (_Float16)(a + p + cm);
  if (j < HH) W2T[j * MM + m] = (_Float16)W2[m * HH + j];  // W2T[col][k]
  if (m < HH) out[j * HH + m] = 0.f;
}

// grid NIGRP*JSPLIT (=3072), block 64 (1 wave). Wave: i0..i0+2, 16 j-tiles.
// (64,2): do NOT force 3 waves/SIMD via launch bounds (R2 spill lesson);
// HW gives 3 waves/SIMD automatically if combined reg alloc <= 170.
__global__ __launch_bounds__(64, 2) void pairmlp_max_kernel(
    const _Float16* __restrict__ Q, const _Float16* __restrict__ P,
    const _Float16* __restrict__ W2T, const float* __restrict__ b2,
    float* __restrict__ out)
{
  const int lane = threadIdx.x;
  const int quad = lane >> 4;   // 0..3
  const int lcol = lane & 15;
  const int ig = blockIdx.x % NIGRP;
  const int js = blockIdx.x / NIGRP;
  const int i0 = ig * NI;

  // B fragments from fp16 W2T: bfrag[ct][ks] = W2T[ct*16+lcol][ks*32+quad*8 ..+8]
  half8 bfrag[4][4];
  #pragma unroll
  for (int ct = 0; ct < 4; ++ct) {
    const _Float16* wrow = W2T + (ct * 16 + lcol) * MM + quad * 8;
    #pragma unroll
    for (int ks = 0; ks < 4; ++ks)
      bfrag[ct][ks] = *(const half8*)(wrow + ks * 32);
  }

  // P fragments for NI i's: lane's A-frag k-slots (8 halfs per ks)
  half8 pv[NI][4];
  #pragma unroll
  for (int ii = 0; ii < NI; ++ii) {
    const _Float16* prow = P + (i0 + ii) * MM + quad * 8;
    #pragma unroll
    for (int ks = 0; ks < 4; ++ks)
      pv[ii][ks] = *(const half8*)(prow + ks * 32);
  }

  float rmax[NI][4];
  #pragma unroll
  for (int ii = 0; ii < NI; ++ii)
    #pragma unroll
    for (int ct = 0; ct < 4; ++ct) rmax[ii][ct] = -1e30f;

  const int jt0 = js * NTILE;
  const _Float16* qbase = Q + (jt0 * 16 + lcol) * MM + quad * 8;  // + t*16*MM + ks*32

  const half8 hz = 0;
  const f32x4 zc = {0.f, 0.f, 0.f, 0.f};

  // one j-tile: A-frag = relu(q - pv), 48 MFMAs (ks=0 peeled with zero C),
  // per-tile max folded into rmax (b2 + relu deferred to epilogue)
  #define PROCESS_TILE(QT)                                                        \
    do {                                                                          \
      f32x4 acc[NI][4];                                                           \
      _Pragma("unroll")                                                           \
      for (int ii = 0; ii < NI; ++ii) {                                           \
        half8 s = (QT)[0] - pv[ii][0];                                            \
        s = __builtin_elementwise_max(s, hz);                                     \
        _Pragma("unroll")                                                         \
        for (int ct = 0; ct < 4; ++ct)                                            \
          acc[ii][ct] = __builtin_amdgcn_mfma_f32_16x16x32_f16(s, bfrag[ct][0], zc, 0, 0, 0); \
      }                                                                           \
      _Pragma("unroll")                                                           \
      for (int ks = 1; ks < 4; ++ks) {                                            \
        _Pragma("unroll")                                                         \
        for (int ii = 0; ii < NI; ++ii) {                                         \
          half8 s = (QT)[ks] - pv[ii][ks];                                        \
          s = __builtin_elementwise_max(s, hz);                                   \
          _Pragma("unroll")                                                       \
          for (int ct = 0; ct < 4; ++ct)                                          \
            acc[ii][ct] = __builtin_amdgcn_mfma_f32_16x16x32_f16(s, bfrag[ct][ks], acc[ii][ct], 0, 0, 0); \
        }                                                                         \
      }                                                                           \
      _Pragma("unroll")                                                           \
      for (int ii = 0; ii < NI; ++ii)                                             \
        _Pragma("unroll")                                                         \
        for (int ct = 0; ct < 4; ++ct) {                                          \
          const float m01 = fmaxf(acc[ii][ct][0], acc[ii][ct][1]);                \
          const float m23 = fmaxf(acc[ii][ct][2], acc[ii][ct][3]);                \
          rmax[ii][ct] = fmaxf(rmax[ii][ct], fmaxf(m01, m23));                    \
        }                                                                         \
    } while (0)

  half8 qa[4], qb[4];
  #pragma unroll
  for (int ks = 0; ks < 4; ++ks) qa[ks] = *(const half8*)(qbase + ks * 32);

  for (int t = 0; t < NTILE; t += 2) {
    // prefetch tile t+1 into qb
    const _Float16* q1 = qbase + (t + 1) * 16 * MM;
    #pragma unroll
    for (int ks = 0; ks < 4; ++ks) qb[ks] = *(const half8*)(q1 + ks * 32);

    PROCESS_TILE(qa);

    // prefetch tile t+2 into qa (clamped dummy on last pass; data unused)
    const int t2 = (t + 2 < NTILE) ? (t + 2) : 0;
    const _Float16* q2 = qbase + t2 * 16 * MM;
    #pragma unroll
    for (int ks = 0; ks < 4; ++ks) qa[ks] = *(const half8*)(q2 + ks * 32);

    PROCESS_TILE(qb);
  }
  #undef PROCESS_TILE

  // combine quad-groups (different j rows, same col), then b2 + relu + atomic max
  #pragma unroll
  for (int ii = 0; ii < NI; ++ii)
    #pragma unroll
    for (int ct = 0; ct < 4; ++ct) {
      float v = rmax[ii][ct];
      v = fmaxf(v, __shfl_xor(v, 16, 64));
      v = fmaxf(v, __shfl_xor(v, 32, 64));
      v = fmaxf(v + b2[ct * 16 + lcol], 0.f);
      if (quad == 0)
        atomicMax((unsigned*)(out + (i0 + ii) * HH + ct * 16 + lcol), __float_as_uint(v));
    }
}

extern "C" void kernel_launch(void* const* d_in, const int* in_sizes, int n_in,
                              void* d_out, int out_size, void* d_ws, size_t ws_size,
                              hipStream_t stream) {
  const float* hidden = (const float*)d_in[0];
  const float* gt     = (const float*)d_in[1];
  const float* We     = (const float*)d_in[2];
  const float* be     = (const float*)d_in[3];
  const float* W1     = (const float*)d_in[4];
  const float* b1     = (const float*)d_in[5];
  const float* W2     = (const float*)d_in[6];
  const float* b2     = (const float*)d_in[7];
  float* out = (float*)d_out;

  _Float16* Qh  = (_Float16*)d_ws;    // NN*MM fp16 (384KB)
  _Float16* Ph  = Qh + NN * MM;       // NN*MM fp16 (384KB)
  _Float16* W2T = Ph + NN * MM;       // HH*MM fp16 (16KB)

  precompute_kernel<<<NN, 128, 0, stream>>>(hidden, gt, We, be, W1, b1, W2, Qh, Ph, W2T, out);
  pairmlp_max_kernel<<<NIGRP * JSPLIT, 64, 0, stream>>>(Qh, Ph, W2T, b2, out);
}